// Round 14
// baseline (294.920 us; speedup 1.0000x reference)
//
#include <hip/hip_runtime.h>
#include <cstdint>
#include <cstddef>

typedef unsigned short u16;
typedef __bf16 bf16x8 __attribute__((ext_vector_type(8)));
typedef float f32x4 __attribute__((ext_vector_type(4)));

#define KOFF 27
#define EPSBN 1e-5f

__device__ inline u16 f2bf(float f) {
  unsigned int u = __float_as_uint(f);
  unsigned int r = (u + 0x7FFFu + ((u >> 16) & 1u)) >> 16;  // RNE
  return (u16)r;
}
__device__ inline float bf2f(u16 h) {
  return __uint_as_float(((unsigned int)h) << 16);
}

// ---------------- fused prep kernel ----------------
// blocks [0, gN): transpose nbr [N,27] -> nbrT [27,N]; plane 27 = all -1
//   (consumed harmlessly by the k+2 id prefetch at k=25).
// blocks [gN, gN+gW): pack W1 into MFMA B-frag order (bf16)
// blocks [gN+gW, gN+2gW): pack W2
// blocks [gN+2gW, ...): cast feats->bf16 (first block also zeroes stats[256])
__global__ void k_prep(const float* __restrict__ feats, const float* __restrict__ W1,
                       const float* __restrict__ W2, const int* __restrict__ nbr,
                       u16* __restrict__ featsb, u16* __restrict__ w1p,
                       u16* __restrict__ w2p, int* __restrict__ nbrT,
                       float* __restrict__ stats, int N, int gN, int gW, int n4) {
  __shared__ int L[64 * KOFF];
  const int t = threadIdx.x;
  const int bid = blockIdx.x;

  if (bid < gN) {  // neighbor transpose
    const int v0 = bid * 64;
    const int nv = min(64, N - v0);
    const int cnt = nv * KOFF;
    for (int i = t; i < cnt; i += 256) L[i] = nbr[(size_t)v0 * KOFF + i];
    __syncthreads();
    for (int i = t; i < KOFF * 64; i += 256) {
      int k = i >> 6, j = i & 63;
      if (j < nv) nbrT[(size_t)k * N + v0 + j] = L[j * KOFF + k];
    }
    if (t < nv) nbrT[(size_t)KOFF * N + v0 + t] = -1;  // plane 27 padding
    return;
  }
  if (bid < gN + 2 * gW) {  // weight pack
    const int wi = bid - gN;
    const bool second = wi >= gW;
    const float* W = second ? W2 : W1;
    u16* Wp = second ? w2p : w1p;
    const int tid = (second ? wi - gW : wi) * 256 + t;
    if (tid >= KOFF * 4096) return;
    const int k = tid >> 12;
    const int rem = tid & 4095;
    const int slot = rem >> 3;
    const int e = rem & 7;
    const int ks = slot >> 8;
    const int ct = (slot >> 6) & 3;
    const int lane = slot & 63;
    const int j = ks * 32 + ((lane >> 4) << 3) + e;
    const int c = ct * 16 + (lane & 15);
    Wp[tid] = f2bf(W[(k * 64 + j) * 64 + c]);
    return;
  }
  // feats cast
  const int idx = bid - gN - 2 * gW;
  if (idx == 0) stats[t] = 0.f;
  const int i = idx * 256 + t;
  if (i >= n4) return;
  const float4 v = reinterpret_cast<const float4*>(feats)[i];
  ushort4 o;
  o.x = f2bf(v.x); o.y = f2bf(v.y); o.z = f2bf(v.z); o.w = f2bf(v.w);
  reinterpret_cast<ushort4*>(featsb)[i] = o;
}

// ---------------- conv kernel (R2 body + refill-interleave + setprio) ----------------
// Block 256 = 4 waves; each wave owns 64 voxels x all 64 output channels.
// Barrier-free. Per k: B(k) frags -> [setprio1] MFMA ks0 (a0) [setprio0] ->
// refill a0 <- A(k+1) low -> [setprio1] MFMA ks1 (a1) [setprio0] -> refill a1
// -> prefetch ids(k+2). Gathers get >=300cyc of MFMA+issue to land instead of
// being consumed in-iteration. Isolated-lever evidence: R7(refill+setprio on
// int4/swizzle base)=113us vs R9(same base without)=150us; register-neutral
// (VGPR 84 both). NO int4, NO swizzle (R9: +55us pair), NO barriers.
// Epilogue: bf16 paired store (R13, WRITE-halving) + fused BN stats.
__launch_bounds__(256, 3)
__global__ void k_conv(const u16* __restrict__ F, const u16* __restrict__ Wp,
                       const int* __restrict__ nbrT, u16* __restrict__ rawout,
                       float* __restrict__ stats, int N) {
  const int t = threadIdx.x;
  const int w = t >> 6;
  const int lane = t & 63;
  const int vbase = blockIdx.x * 256 + (w << 6) + (lane & 15);
  const int ch = (lane >> 4) << 3;  // A-frag channel offset (elements)

  f32x4 acc[4][4];
#pragma unroll
  for (int m = 0; m < 4; ++m)
#pragma unroll
    for (int c = 0; c < 4; ++c) acc[m][c] = (f32x4){0.f, 0.f, 0.f, 0.f};

  bool vok[4];
  int nid[4];
#pragma unroll
  for (int m = 0; m < 4; ++m) {
    const int v = vbase + (m << 4);
    vok[m] = v < N;
    nid[m] = vok[m] ? nbrT[v] : -1;  // ids for k=0
  }

  // prologue: A(0) into a0/a1, then nid <- ids(1)
  bf16x8 a0[4], a1[4];
#pragma unroll
  for (int m = 0; m < 4; ++m) {
    a0[m] = (bf16x8){};
    a1[m] = (bf16x8){};
    if (nid[m] >= 0) {
      const u16* fr = F + ((size_t)(unsigned)nid[m] << 6) + ch;
      a0[m] = *reinterpret_cast<const bf16x8*>(fr);
      a1[m] = *reinterpret_cast<const bf16x8*>(fr + 32);
    }
  }
  {
    const int* nk = nbrT + (size_t)N;
#pragma unroll
    for (int m = 0; m < 4; ++m) nid[m] = vok[m] ? nk[vbase + (m << 4)] : -1;
  }

  const u16* bp = Wp + ((size_t)lane << 3);

  // main loop: k = 0..25 (refill pipelined one k ahead)
  for (int k = 0; k < 26; ++k) {
    // B(k) fragments (broadcast across waves -> L1/L2 hits)
    bf16x8 bfr[2][4];
    {
      const u16* bk = bp + ((size_t)k << 12);
#pragma unroll
      for (int ks = 0; ks < 2; ++ks)
#pragma unroll
        for (int c = 0; c < 4; ++c)
          bfr[ks][c] = *reinterpret_cast<const bf16x8*>(bk + (ks << 11) + (c << 9));
    }
    const int ids[4] = {nid[0], nid[1], nid[2], nid[3]};  // ids for k+1
    // MFMA half-cluster ks=0 (consumes a0 of k)
    __builtin_amdgcn_s_setprio(1);
#pragma unroll
    for (int m = 0; m < 4; ++m)
#pragma unroll
      for (int c = 0; c < 4; ++c)
        acc[m][c] = __builtin_amdgcn_mfma_f32_16x16x32_bf16(a0[m], bfr[0][c], acc[m][c], 0, 0, 0);
    __builtin_amdgcn_s_setprio(0);
    // refill a0 <- A(k+1) low half
    const u16* srcs[4];
#pragma unroll
    for (int m = 0; m < 4; ++m) {
      bf16x8 v = (bf16x8){};
      if (ids[m] >= 0) {
        srcs[m] = F + ((size_t)(unsigned)ids[m] << 6) + ch;
        v = *reinterpret_cast<const bf16x8*>(srcs[m]);
      }
      a0[m] = v;
    }
    // MFMA half-cluster ks=1 (consumes a1 of k)
    __builtin_amdgcn_s_setprio(1);
#pragma unroll
    for (int m = 0; m < 4; ++m)
#pragma unroll
      for (int c = 0; c < 4; ++c)
        acc[m][c] = __builtin_amdgcn_mfma_f32_16x16x32_bf16(a1[m], bfr[1][c], acc[m][c], 0, 0, 0);
    __builtin_amdgcn_s_setprio(0);
    // refill a1 <- A(k+1) high half
#pragma unroll
    for (int m = 0; m < 4; ++m) {
      bf16x8 v = (bf16x8){};
      if (ids[m] >= 0) v = *reinterpret_cast<const bf16x8*>(srcs[m] + 32);
      a1[m] = v;
    }
    // prefetch ids(k+2); plane 27 = -1 padding
    {
      const int* nk = nbrT + (size_t)(k + 2) * N;
#pragma unroll
      for (int m = 0; m < 4; ++m) nid[m] = vok[m] ? nk[vbase + (m << 4)] : -1;
    }
  }

  // epilogue: k = 26 (a0/a1 already hold A(26))
  {
    bf16x8 bfr[2][4];
    const u16* bk = bp + ((size_t)26 << 12);
#pragma unroll
    for (int ks = 0; ks < 2; ++ks)
#pragma unroll
      for (int c = 0; c < 4; ++c)
        bfr[ks][c] = *reinterpret_cast<const bf16x8*>(bk + (ks << 11) + (c << 9));
    __builtin_amdgcn_s_setprio(1);
#pragma unroll
    for (int m = 0; m < 4; ++m)
#pragma unroll
      for (int c = 0; c < 4; ++c)
        acc[m][c] = __builtin_amdgcn_mfma_f32_16x16x32_bf16(a0[m], bfr[0][c], acc[m][c], 0, 0, 0);
#pragma unroll
    for (int m = 0; m < 4; ++m)
#pragma unroll
      for (int c = 0; c < 4; ++c)
        acc[m][c] = __builtin_amdgcn_mfma_f32_16x16x32_bf16(a1[m], bfr[1][c], acc[m][c], 0, 0, 0);
    __builtin_amdgcn_s_setprio(0);
  }

  // ---- bf16 paired store + fused BN-stat partial reduction (R13 epilogue) ----
  const int row0 = blockIdx.x * 256 + (w << 6) + ((lane >> 4) << 2);
  const bool evenlane = (lane & 1) == 0;
#pragma unroll
  for (int m = 0; m < 4; ++m) {
#pragma unroll
    for (int e = 0; e < 4; ++e) {
      const int v = row0 + (m << 4) + e;
#pragma unroll
      for (int c = 0; c < 4; ++c) {
        const unsigned myb = (unsigned)f2bf(acc[m][c][e]);
        const unsigned ob = (unsigned)__shfl_xor((int)myb, 1, 64);
        if (evenlane && v < N) {
          const int col = (c << 4) + (lane & 15);
          *reinterpret_cast<unsigned*>(rawout + ((size_t)v << 6) + col) = myb | (ob << 16);
        }
      }
    }
  }

  __shared__ float sred[4][128];
#pragma unroll
  for (int c = 0; c < 4; ++c) {
    float s = 0.f, q = 0.f;
#pragma unroll
    for (int m = 0; m < 4; ++m)
#pragma unroll
      for (int e = 0; e < 4; ++e) {
        const float x = acc[m][c][e];  // OOB rows contribute exact 0
        s += x;
        q += x * x;
      }
    s += __shfl_xor(s, 16, 64);
    s += __shfl_xor(s, 32, 64);
    q += __shfl_xor(q, 16, 64);
    q += __shfl_xor(q, 32, 64);
    if (lane < 16) {
      sred[w][(c << 4) + lane] = s;
      sred[w][64 + (c << 4) + lane] = q;
    }
  }
  __syncthreads();
  if (t < 128) {
    const float tot = sred[0][t] + sred[1][t] + sred[2][t] + sred[3][t];
    atomicAdd(&stats[t], tot);
  }
}

// ---------------- BN apply (k_final fused; raw input is bf16, 8 elems/thread) ----------------

// x_net = relu(raw*sc+bi) -> bf16
__global__ void k_apply1(const u16* __restrict__ raw, const float* __restrict__ stats,
                         const float* __restrict__ gamma, const float* __restrict__ beta,
                         u16* __restrict__ xb, int n8, float invN) {
  int i = blockIdx.x * 256 + threadIdx.x;
  if (i >= n8) return;
  const int c0 = (i & 7) << 3;  // first of this thread's 8 channels
  float sc[8], bi[8];
#pragma unroll
  for (int j = 0; j < 8; ++j) {
    const int c = c0 + j;
    const float mu = stats[c] * invN;
    const float var = stats[64 + c] * invN - mu * mu;
    sc[j] = gamma[c] * rsqrtf(var + EPSBN);
    bi[j] = beta[c] - mu * sc[j];
  }
  const uint4 rv = reinterpret_cast<const uint4*>(raw)[i];
  const unsigned vals[4] = {rv.x, rv.y, rv.z, rv.w};
  unsigned ov[4];
#pragma unroll
  for (int j = 0; j < 4; ++j) {
    const float lo = bf2f((u16)(vals[j] & 0xffff));
    const float hi = bf2f((u16)(vals[j] >> 16));
    const float y0 = fmaxf(0.f, lo * sc[2 * j] + bi[2 * j]);
    const float y1 = fmaxf(0.f, hi * sc[2 * j + 1] + bi[2 * j + 1]);
    ov[j] = (unsigned)f2bf(y0) | ((unsigned)f2bf(y1) << 16);
  }
  reinterpret_cast<uint4*>(xb)[i] = make_uint4(ov[0], ov[1], ov[2], ov[3]);
}

// out = x_net + relu(raw*sc+bi)   (raw, x_net bf16 -> out f32)
__global__ void k_apply2(const u16* __restrict__ raw, const float* __restrict__ stats,
                         const float* __restrict__ gamma, const float* __restrict__ beta,
                         const u16* __restrict__ xb, float* __restrict__ out, int n8,
                         float invN) {
  int i = blockIdx.x * 256 + threadIdx.x;
  if (i >= n8) return;
  const int c0 = (i & 7) << 3;
  float sc[8], bi[8];
#pragma unroll
  for (int j = 0; j < 8; ++j) {
    const int c = c0 + j;
    const float mu = stats[c] * invN;
    const float var = stats[64 + c] * invN - mu * mu;
    sc[j] = gamma[c] * rsqrtf(var + EPSBN);
    bi[j] = beta[c] - mu * sc[j];
  }
  const uint4 rv = reinterpret_cast<const uint4*>(raw)[i];
  const uint4 xv = reinterpret_cast<const uint4*>(xb)[i];
  const unsigned rvals[4] = {rv.x, rv.y, rv.z, rv.w};
  const unsigned xvals[4] = {xv.x, xv.y, xv.z, xv.w};
  float o[8];
#pragma unroll
  for (int j = 0; j < 4; ++j) {
    const float rlo = bf2f((u16)(rvals[j] & 0xffff));
    const float rhi = bf2f((u16)(rvals[j] >> 16));
    o[2 * j] = bf2f((u16)(xvals[j] & 0xffff)) + fmaxf(0.f, rlo * sc[2 * j] + bi[2 * j]);
    o[2 * j + 1] = bf2f((u16)(xvals[j] >> 16)) + fmaxf(0.f, rhi * sc[2 * j + 1] + bi[2 * j + 1]);
  }
  reinterpret_cast<float4*>(out)[2 * i] = make_float4(o[0], o[1], o[2], o[3]);
  reinterpret_cast<float4*>(out)[2 * i + 1] = make_float4(o[4], o[5], o[6], o[7]);
}

// ---------------- host ----------------

extern "C" void kernel_launch(void* const* d_in, const int* in_sizes, int n_in,
                              void* d_out, int out_size, void* d_ws, size_t ws_size,
                              hipStream_t stream) {
  const float* feats = (const float*)d_in[0];
  const float* W1 = (const float*)d_in[1];
  const float* g1 = (const float*)d_in[2];
  const float* b1 = (const float*)d_in[3];
  const float* W2 = (const float*)d_in[4];
  const float* g2 = (const float*)d_in[5];
  const float* b2 = (const float*)d_in[6];
  const int* nbr = (const int*)d_in[7];
  const int N = in_sizes[0] / 64;

  char* ws = (char*)d_ws;
  size_t off = 0;
  auto alloc = [&](size_t bytes) {
    void* p = ws + off;
    off = (off + bytes + 255) & ~(size_t)255;
    return p;
  };
  u16* featsb = (u16*)alloc((size_t)N * 64 * 2);
  u16* xnetb = (u16*)alloc((size_t)N * 64 * 2);
  u16* w1p = (u16*)alloc((size_t)KOFF * 4096 * 2);
  u16* w2p = (u16*)alloc((size_t)KOFF * 4096 * 2);
  float* stats = (float*)alloc(256 * 4);  // [s1 q1 s2 q2] x 64
  int* nbrT = (int*)alloc((size_t)(KOFF + 1) * N * 4);  // +plane27(-1)

  u16* raw1 = (u16*)d_out;  // conv1 raw bf16 scribbled into d_out (overwritten later)
  u16* raw2 = featsb;       // conv2 raw bf16 reuses dead conv1-input buffer
  float* outf = (float*)d_out;

  const int n4 = N * 16;
  const int n8 = N * 8;
  const float invN = 1.0f / (float)N;
  const int gN = (N + 63) / 64;
  const int gPrep = (n4 + 255) / 256;
  const int gApply = (n8 + 255) / 256;
  const int gW = (KOFF * 4096 + 255) / 256;
  const int gConv = (N + 255) / 256;

  k_prep<<<gN + 2 * gW + gPrep, 256, 0, stream>>>(feats, W1, W2, nbr, featsb, w1p, w2p,
                                                  nbrT, stats, N, gN, gW, n4);

  k_conv<<<gConv, 256, 0, stream>>>(featsb, w1p, nbrT, raw1, stats, N);
  k_apply1<<<gApply, 256, 0, stream>>>(raw1, stats, g1, b1, xnetb, n8, invN);

  k_conv<<<gConv, 256, 0, stream>>>(xnetb, w2p, nbrT, raw2, stats + 128, N);
  k_apply2<<<gApply, 256, 0, stream>>>(raw2, stats + 128, g2, b2, xnetb, outf, n8, invN);
}

// Round 15
// 247.511 us; speedup vs baseline: 1.1915x; 1.1915x over previous
//
#include <hip/hip_runtime.h>
#include <cstdint>
#include <cstddef>

typedef unsigned short u16;
typedef __bf16 bf16x8 __attribute__((ext_vector_type(8)));
typedef float f32x4 __attribute__((ext_vector_type(4)));

#define KOFF 27
#define EPSBN 1e-5f

__device__ inline u16 f2bf(float f) {
  unsigned int u = __float_as_uint(f);
  unsigned int r = (u + 0x7FFFu + ((u >> 16) & 1u)) >> 16;  // RNE
  return (u16)r;
}
__device__ inline float bf2f(u16 h) {
  return __uint_as_float(((unsigned int)h) << 16);
}

// ---------------- fused prep kernel ----------------
// blocks [0, gN): transpose nbr [N,27] -> nbrT [27,N] (coalesced both sides)
// blocks [gN, gN+gW): pack W1 into MFMA B-frag order (bf16)
// blocks [gN+gW, gN+2gW): pack W2
// blocks [gN+2gW, ...): cast feats->bf16 (first block also zeroes stats[256])
__global__ void k_prep(const float* __restrict__ feats, const float* __restrict__ W1,
                       const float* __restrict__ W2, const int* __restrict__ nbr,
                       u16* __restrict__ featsb, u16* __restrict__ w1p,
                       u16* __restrict__ w2p, int* __restrict__ nbrT,
                       float* __restrict__ stats, int N, int gN, int gW, int n4) {
  __shared__ int L[64 * KOFF];
  const int t = threadIdx.x;
  const int bid = blockIdx.x;

  if (bid < gN) {  // neighbor transpose
    const int v0 = bid * 64;
    const int nv = min(64, N - v0);
    const int cnt = nv * KOFF;
    for (int i = t; i < cnt; i += 256) L[i] = nbr[(size_t)v0 * KOFF + i];
    __syncthreads();
    for (int i = t; i < KOFF * 64; i += 256) {
      int k = i >> 6, j = i & 63;
      if (j < nv) nbrT[(size_t)k * N + v0 + j] = L[j * KOFF + k];
    }
    return;
  }
  if (bid < gN + 2 * gW) {  // weight pack
    const int wi = bid - gN;
    const bool second = wi >= gW;
    const float* W = second ? W2 : W1;
    u16* Wp = second ? w2p : w1p;
    const int tid = (second ? wi - gW : wi) * 256 + t;
    if (tid >= KOFF * 4096) return;
    const int k = tid >> 12;
    const int rem = tid & 4095;
    const int slot = rem >> 3;
    const int e = rem & 7;
    const int ks = slot >> 8;
    const int ct = (slot >> 6) & 3;
    const int lane = slot & 63;
    const int j = ks * 32 + ((lane >> 4) << 3) + e;
    const int c = ct * 16 + (lane & 15);
    Wp[tid] = f2bf(W[(k * 64 + j) * 64 + c]);
    return;
  }
  // feats cast
  const int idx = bid - gN - 2 * gW;
  if (idx == 0) stats[t] = 0.f;
  const int i = idx * 256 + t;
  if (i >= n4) return;
  const float4 v = reinterpret_cast<const float4*>(feats)[i];
  ushort4 o;
  o.x = f2bf(v.x); o.y = f2bf(v.y); o.z = f2bf(v.z); o.w = f2bf(v.w);
  reinterpret_cast<ushort4*>(featsb)[i] = o;
}

// ---------------- conv kernel (R2/R10 loop, bf16 paired-store epilogue) ----------------
// Block 256 = 4 waves; each wave owns 64 voxels x all 64 output channels.
// Plain compiler-scheduled, barrier-free, register-direct loop — FINAL.
// Nine structural alternatives measured slower (R3-R9, R11, R14): reg-dbuf,
// 32-voxel tile, LDS-A (x2), LDS-B+barriers, refill+setprio (x2), forced
// 4-waves/SIMD (spills), int4+swizzle. The kernel is dependent-gather
// latency-bound at the 64x64 tile's register-occupancy ceiling (~2.5 waves/
// SIMD); no pipe saturates (MfmaUtil ~27%, HBM ~9%) and no tested technique
// converts the idle capacity. Epilogue: bf16 lane-paired stores (halves WRITE,
// preserves write-combining) + fused BN-stat reduction from exact f32 acc.
__launch_bounds__(256, 3)
__global__ void k_conv(const u16* __restrict__ F, const u16* __restrict__ Wp,
                       const int* __restrict__ nbrT, u16* __restrict__ rawout,
                       float* __restrict__ stats, int N) {
  const int t = threadIdx.x;
  const int w = t >> 6;
  const int lane = t & 63;
  const int vbase = blockIdx.x * 256 + (w << 6) + (lane & 15);
  const int ch = (lane >> 4) << 3;  // A-frag channel offset (elements)

  f32x4 acc[4][4];
#pragma unroll
  for (int m = 0; m < 4; ++m)
#pragma unroll
    for (int c = 0; c < 4; ++c) acc[m][c] = (f32x4){0.f, 0.f, 0.f, 0.f};

  // prefetch k=0 neighbor indices
  int nid[4];
#pragma unroll
  for (int m = 0; m < 4; ++m) {
    const int v = vbase + (m << 4);
    nid[m] = (v < N) ? nbrT[v] : -1;
  }

  const u16* bp = Wp + ((size_t)lane << 3);

#pragma unroll 3
  for (int k = 0; k < KOFF; ++k) {
    // B fragments for this k (broadcast across waves -> L1/L2 hits)
    bf16x8 bfr[2][4];
#pragma unroll
    for (int ks = 0; ks < 2; ++ks)
#pragma unroll
      for (int c = 0; c < 4; ++c)
        bfr[ks][c] = *reinterpret_cast<const bf16x8*>(bp + ((size_t)k << 12) + (ks << 11) + (c << 9));

    // A fragments: direct register gather
    bf16x8 a0[4], a1[4];
#pragma unroll
    for (int m = 0; m < 4; ++m) {
      a0[m] = (bf16x8){};
      a1[m] = (bf16x8){};
      const int id = nid[m];
      if (id >= 0) {
        const u16* fr = F + ((size_t)id << 6) + ch;
        a0[m] = *reinterpret_cast<const bf16x8*>(fr);
        a1[m] = *reinterpret_cast<const bf16x8*>(fr + 32);
      }
    }

    // prefetch next k's indices (latency hidden under the MFMA block)
    if (k + 1 < KOFF) {
      const int* nk = nbrT + (size_t)(k + 1) * N;
#pragma unroll
      for (int m = 0; m < 4; ++m) {
        const int v = vbase + (m << 4);
        nid[m] = (v < N) ? nk[v] : -1;
      }
    }

#pragma unroll
    for (int m = 0; m < 4; ++m)
#pragma unroll
      for (int c = 0; c < 4; ++c)
        acc[m][c] = __builtin_amdgcn_mfma_f32_16x16x32_bf16(a0[m], bfr[0][c], acc[m][c], 0, 0, 0);
#pragma unroll
    for (int m = 0; m < 4; ++m)
#pragma unroll
      for (int c = 0; c < 4; ++c)
        acc[m][c] = __builtin_amdgcn_mfma_f32_16x16x32_bf16(a1[m], bfr[1][c], acc[m][c], 0, 0, 0);
  }

  // ---- bf16 paired store + fused BN-stat partial reduction ----
  const int row0 = blockIdx.x * 256 + (w << 6) + ((lane >> 4) << 2);
  const bool evenlane = (lane & 1) == 0;
#pragma unroll
  for (int m = 0; m < 4; ++m) {
#pragma unroll
    for (int e = 0; e < 4; ++e) {
      const int v = row0 + (m << 4) + e;
#pragma unroll
      for (int c = 0; c < 4; ++c) {
        const unsigned myb = (unsigned)f2bf(acc[m][c][e]);
        const unsigned ob = (unsigned)__shfl_xor((int)myb, 1, 64);
        if (evenlane && v < N) {
          const int col = (c << 4) + (lane & 15);  // even col; u32 covers (col, col+1)
          *reinterpret_cast<unsigned*>(rawout + ((size_t)v << 6) + col) = myb | (ob << 16);
        }
      }
    }
  }

  __shared__ float sred[4][128];
#pragma unroll
  for (int c = 0; c < 4; ++c) {
    float s = 0.f, q = 0.f;
#pragma unroll
    for (int m = 0; m < 4; ++m)
#pragma unroll
      for (int e = 0; e < 4; ++e) {
        const float x = acc[m][c][e];  // OOB rows contribute exact 0
        s += x;
        q += x * x;
      }
    s += __shfl_xor(s, 16, 64);
    s += __shfl_xor(s, 32, 64);
    q += __shfl_xor(q, 16, 64);
    q += __shfl_xor(q, 32, 64);
    if (lane < 16) {
      sred[w][(c << 4) + lane] = s;
      sred[w][64 + (c << 4) + lane] = q;
    }
  }
  __syncthreads();
  if (t < 128) {
    const float tot = sred[0][t] + sred[1][t] + sred[2][t] + sred[3][t];
    atomicAdd(&stats[t], tot);
  }
}

// ---------------- BN apply (k_final fused; raw input is bf16, 8 elems/thread) ----------------

// x_net = relu(raw*sc+bi) -> bf16
__global__ void k_apply1(const u16* __restrict__ raw, const float* __restrict__ stats,
                         const float* __restrict__ gamma, const float* __restrict__ beta,
                         u16* __restrict__ xb, int n8, float invN) {
  int i = blockIdx.x * 256 + threadIdx.x;
  if (i >= n8) return;
  const int c0 = (i & 7) << 3;  // first of this thread's 8 channels
  float sc[8], bi[8];
#pragma unroll
  for (int j = 0; j < 8; ++j) {
    const int c = c0 + j;
    const float mu = stats[c] * invN;
    const float var = stats[64 + c] * invN - mu * mu;
    sc[j] = gamma[c] * rsqrtf(var + EPSBN);
    bi[j] = beta[c] - mu * sc[j];
  }
  const uint4 rv = reinterpret_cast<const uint4*>(raw)[i];
  const unsigned vals[4] = {rv.x, rv.y, rv.z, rv.w};
  unsigned ov[4];
#pragma unroll
  for (int j = 0; j < 4; ++j) {
    const float lo = bf2f((u16)(vals[j] & 0xffff));
    const float hi = bf2f((u16)(vals[j] >> 16));
    const float y0 = fmaxf(0.f, lo * sc[2 * j] + bi[2 * j]);
    const float y1 = fmaxf(0.f, hi * sc[2 * j + 1] + bi[2 * j + 1]);
    ov[j] = (unsigned)f2bf(y0) | ((unsigned)f2bf(y1) << 16);
  }
  reinterpret_cast<uint4*>(xb)[i] = make_uint4(ov[0], ov[1], ov[2], ov[3]);
}

// out = x_net + relu(raw*sc+bi)   (raw, x_net bf16 -> out f32)
__global__ void k_apply2(const u16* __restrict__ raw, const float* __restrict__ stats,
                         const float* __restrict__ gamma, const float* __restrict__ beta,
                         const u16* __restrict__ xb, float* __restrict__ out, int n8,
                         float invN) {
  int i = blockIdx.x * 256 + threadIdx.x;
  if (i >= n8) return;
  const int c0 = (i & 7) << 3;
  float sc[8], bi[8];
#pragma unroll
  for (int j = 0; j < 8; ++j) {
    const int c = c0 + j;
    const float mu = stats[c] * invN;
    const float var = stats[64 + c] * invN - mu * mu;
    sc[j] = gamma[c] * rsqrtf(var + EPSBN);
    bi[j] = beta[c] - mu * sc[j];
  }
  const uint4 rv = reinterpret_cast<const uint4*>(raw)[i];
  const uint4 xv = reinterpret_cast<const uint4*>(xb)[i];
  const unsigned rvals[4] = {rv.x, rv.y, rv.z, rv.w};
  const unsigned xvals[4] = {xv.x, xv.y, xv.z, xv.w};
  float o[8];
#pragma unroll
  for (int j = 0; j < 4; ++j) {
    const float rlo = bf2f((u16)(rvals[j] & 0xffff));
    const float rhi = bf2f((u16)(rvals[j] >> 16));
    o[2 * j] = bf2f((u16)(xvals[j] & 0xffff)) + fmaxf(0.f, rlo * sc[2 * j] + bi[2 * j]);
    o[2 * j + 1] = bf2f((u16)(xvals[j] >> 16)) + fmaxf(0.f, rhi * sc[2 * j + 1] + bi[2 * j + 1]);
  }
  reinterpret_cast<float4*>(out)[2 * i] = make_float4(o[0], o[1], o[2], o[3]);
  reinterpret_cast<float4*>(out)[2 * i + 1] = make_float4(o[4], o[5], o[6], o[7]);
}

// ---------------- host ----------------

extern "C" void kernel_launch(void* const* d_in, const int* in_sizes, int n_in,
                              void* d_out, int out_size, void* d_ws, size_t ws_size,
                              hipStream_t stream) {
  const float* feats = (const float*)d_in[0];
  const float* W1 = (const float*)d_in[1];
  const float* g1 = (const float*)d_in[2];
  const float* b1 = (const float*)d_in[3];
  const float* W2 = (const float*)d_in[4];
  const float* g2 = (const float*)d_in[5];
  const float* b2 = (const float*)d_in[6];
  const int* nbr = (const int*)d_in[7];
  const int N = in_sizes[0] / 64;

  char* ws = (char*)d_ws;
  size_t off = 0;
  auto alloc = [&](size_t bytes) {
    void* p = ws + off;
    off = (off + bytes + 255) & ~(size_t)255;
    return p;
  };
  u16* featsb = (u16*)alloc((size_t)N * 64 * 2);
  u16* xnetb = (u16*)alloc((size_t)N * 64 * 2);
  u16* w1p = (u16*)alloc((size_t)KOFF * 4096 * 2);
  u16* w2p = (u16*)alloc((size_t)KOFF * 4096 * 2);
  float* stats = (float*)alloc(256 * 4);  // [s1 q1 s2 q2] x 64
  int* nbrT = (int*)alloc((size_t)KOFF * N * 4);

  u16* raw1 = (u16*)d_out;  // conv1 raw bf16 scribbled into d_out (overwritten later)
  u16* raw2 = featsb;       // conv2 raw bf16 reuses dead conv1-input buffer
  float* outf = (float*)d_out;

  const int n4 = N * 16;
  const int n8 = N * 8;
  const float invN = 1.0f / (float)N;
  const int gN = (N + 63) / 64;
  const int gPrep = (n4 + 255) / 256;
  const int gApply = (n8 + 255) / 256;
  const int gW = (KOFF * 4096 + 255) / 256;
  const int gConv = (N + 255) / 256;

  k_prep<<<gN + 2 * gW + gPrep, 256, 0, stream>>>(feats, W1, W2, nbr, featsb, w1p, w2p,
                                                  nbrT, stats, N, gN, gW, n4);

  k_conv<<<gConv, 256, 0, stream>>>(featsb, w1p, nbrT, raw1, stats, N);
  k_apply1<<<gApply, 256, 0, stream>>>(raw1, stats, g1, b1, xnetb, n8, invN);

  k_conv<<<gConv, 256, 0, stream>>>(xnetb, w2p, nbrT, raw2, stats + 128, N);
  k_apply2<<<gApply, 256, 0, stream>>>(raw2, stats + 128, g2, b2, xnetb, outf, n8, invN);
}